// Round 10
// baseline (518.151 us; speedup 1.0000x reference)
//
#include <hip/hip_runtime.h>
#include <hip/hip_bf16.h>

// DeepSeekMoE: B=4,S=2048,D=1024,H=1024,E=7,NS=1,topk=3. N=8192 tokens.
#define N_TOK 8192
#define DIM   1024
#define NE    7
#define MT_TILES 136   // <= 103 routed + 32 shared + slack; grid 136*8 % 8 == 0

typedef __attribute__((ext_vector_type(8))) short bf16x8;
typedef __attribute__((ext_vector_type(4))) float f32x4;

typedef __attribute__((address_space(3))) ushort lds_us_t;
typedef __attribute__((address_space(1))) const ushort glb_us_t;

__device__ __forceinline__ void gll16(const ushort* g, ushort* l) {
    __builtin_amdgcn_global_load_lds((glb_us_t*)g, (lds_us_t*)l, 16, 0, 0);
}

__device__ __forceinline__ unsigned short f2bf(float f) {
    unsigned int u = __builtin_bit_cast(unsigned int, f);
    u += 0x7fffu + ((u >> 16) & 1u);   // RNE
    return (unsigned short)(u >> 16);
}

__device__ __forceinline__ float bf2f(unsigned short b) {
    unsigned int u = ((unsigned int)b) << 16;
    return __builtin_bit_cast(float, u);
}

__device__ __forceinline__ float siluf(float v) { return v / (1.f + __expf(-v)); }

// ---------------- gate: logits -> softmax -> top3 -> renorm weights ----------
__global__ void __launch_bounds__(256)
gate_kernel(const float* __restrict__ x, const float* __restrict__ gw,
            const float* __restrict__ gb, const float* __restrict__ bia,
            int* __restrict__ topk_e, float* __restrict__ topk_w,
            int* __restrict__ counts, ushort* __restrict__ xb)
{
    __shared__ float gwT[NE][DIM];   // 28 KB
    __shared__ int cnt[NE];
    const int tid = threadIdx.x;
    if (tid < NE) cnt[tid] = 0;
    for (int t = tid; t < NE * DIM; t += 256) {
        int d = t / NE, e = t - d * NE;
        gwT[e][d] = gw[t];
    }
    __syncthreads();

    const int lane = tid & 63, wid = tid >> 6;
#pragma unroll
    for (int tt = 0; tt < 4; tt++) {
        const int n = blockIdx.x * 16 + wid * 4 + tt;
        const float4* xr = (const float4*)(x + (size_t)n * DIM);
        ushort4* xo = (ushort4*)(xb + (size_t)n * DIM);
        float p[NE];
#pragma unroll
        for (int e = 0; e < NE; e++) p[e] = 0.f;
#pragma unroll
        for (int it = 0; it < 4; it++) {
            int i4 = it * 64 + lane;
            float4 v = xr[i4];
            ushort4 o;
            o.x = f2bf(v.x); o.y = f2bf(v.y); o.z = f2bf(v.z); o.w = f2bf(v.w);
            xo[i4] = o;
            int d = i4 * 4;
#pragma unroll
            for (int e = 0; e < NE; e++) {
                float4 g = *(const float4*)&gwT[e][d];
                p[e] += v.x * g.x + v.y * g.y + v.z * g.z + v.w * g.w;
            }
        }
#pragma unroll
        for (int e = 0; e < NE; e++)
            for (int off = 32; off; off >>= 1) p[e] += __shfl_xor(p[e], off);
        if (lane == 0) {
            float l[NE], m = -1e30f;
#pragma unroll
            for (int e = 0; e < NE; e++) { l[e] = p[e] + gb[e]; m = fmaxf(m, l[e]); }
            float s = 0.f;
#pragma unroll
            for (int e = 0; e < NE; e++) { l[e] = __expf(l[e] - m); s += l[e]; }
            float inv = 1.f / s;
#pragma unroll
            for (int e = 0; e < NE; e++) l[e] *= inv;          // probs
            float adj[NE]; bool used[NE];
#pragma unroll
            for (int e = 0; e < NE; e++) { adj[e] = l[e] + bia[e]; used[e] = false; }
            int sel[3]; float w[3]; float ws = 0.f;
            for (int k = 0; k < 3; k++) {
                int b = -1; float bv = -1e30f;
                for (int e = 0; e < NE; e++)
                    if (!used[e] && adj[e] > bv) { bv = adj[e]; b = e; }
                used[b] = true; sel[k] = b; w[k] = l[b]; ws += w[k];
            }
            float iws = 1.f / ws;
            for (int k = 0; k < 3; k++) {
                topk_e[n * 3 + k] = sel[k];
                topk_w[n * 3 + k] = w[k] * iws;
                atomicAdd(&cnt[sel[k]], 1);
            }
        }
    }
    __syncthreads();
    if (tid < NE) atomicAdd(&counts[tid], cnt[tid]);
}

// --------- setup (1 thread): 256-pad scan + tile list (pads memset'd) --------
__global__ void setup_kernel(int* __restrict__ ctrl)
{
    if (threadIdx.x != 0 || blockIdx.x != 0) return;
    int* counts = ctrl + 8; int* cursors = ctrl + 16; int* tiles = ctrl + 32;
    int nm = 0, off = 0;
    for (int e = 0; e < NE; e++) {
        int c = counts[e];
        int padc = (c + 255) & ~255;
        cursors[e] = off;
        for (int t = 0; t < padc; t += 256) { tiles[nm*2] = e; tiles[nm*2+1] = off + t; nm++; }
        off += padc;
    }
    ctrl[2] = off;                       // shared_base
    for (int t = 0; t < N_TOK; t += 256) { tiles[nm*2] = NE; tiles[nm*2+1] = off + t; nm++; }
    ctrl[1] = off + N_TOK;               // total rows
    ctrl[0] = nm;                        // tile count
}

// --------- identity fill for shared region -----------------------------------
__global__ void ident_kernel(const int* __restrict__ ctrl, int* __restrict__ row_tok)
{
    int n = blockIdx.x * 256 + threadIdx.x;
    row_tok[ctrl[2] + n] = n;
}

// --------- scatter: token -> per-expert padded slots (+ inverse map) ---------
__global__ void scatter_kernel(const int* __restrict__ topk_e, const float* __restrict__ topk_w,
                               int* __restrict__ ctrl, int* __restrict__ row_tok,
                               int* __restrict__ slots)
{
    int n = blockIdx.x * blockDim.x + threadIdx.x;
    if (n >= N_TOK) return;
    int* cursors = ctrl + 16;
    for (int k = 0; k < 3; k++) {
        int e = topk_e[n * 3 + k];
        int slot = atomicAdd(&cursors[e], 1);
        row_tok[slot] = n;
        slots[n * 3 + k] = slot;
    }
}

// --------- transpose+convert weights to B^T bf16 -----------------------------
__global__ void transpose_convert(const float* __restrict__ w1, const float* __restrict__ wg,
                                  const float* __restrict__ w2, const float* __restrict__ sw1,
                                  const float* __restrict__ sw2,
                                  ushort* __restrict__ w1T, ushort* __restrict__ wgT,
                                  ushort* __restrict__ w2T)
{
    int z = blockIdx.z;
    const float* src; ushort* dst;
    if (z < 7)       { src = w1 + (size_t)z * (DIM*DIM);        dst = w1T + (size_t)z * (DIM*DIM); }
    else if (z < 14) { src = wg + (size_t)(z - 7) * (DIM*DIM);  dst = wgT + (size_t)(z - 7) * (DIM*DIM); }
    else if (z < 21) { src = w2 + (size_t)(z - 14) * (DIM*DIM); dst = w2T + (size_t)(z - 14) * (DIM*DIM); }
    else if (z == 21){ src = sw1; dst = w1T + (size_t)NE * (DIM*DIM); }
    else             { src = sw2; dst = w2T + (size_t)NE * (DIM*DIM); }
    __shared__ float t[32][33];
    int bx = blockIdx.x * 32, by = blockIdx.y * 32;
    int lx = threadIdx.x & 31, ly = threadIdx.x >> 5;
#pragma unroll
    for (int i = 0; i < 32; i += 8)
        t[ly + i][lx] = src[(size_t)(by + ly + i) * DIM + bx + lx];
    __syncthreads();
#pragma unroll
    for (int i = 0; i < 32; i += 8) {
        int r = ly + i;
        dst[(size_t)(bx + r) * DIM + by + lx] = f2bf(t[lx][r]);
    }
}

// XCD-aware remap: XCD k owns x-tiles [17k,17k+17) x all 8 col-blocks.
__device__ __forceinline__ void xcd_remap(int& bx, int& col0) {
    int L = blockIdx.x + blockIdx.y * MT_TILES;
    int D = (L & 7) * MT_TILES + (L >> 3);
    bx = D >> 3;
    col0 = (D & 7) * 128;
}

// ============ phase-split GEMM (T3+T4): BM=256 BN=128 BK=64 ==================
// 8 waves as 2M x 4N (wave tile 128x32). LDS per K-tile buffer:
//   A [0,16384): two 8192-el [256][32] swizzled subtiles (ks=0,1)
//   B1 [16384,24576): two 4096-el [128][32] subtiles; (g1) B2 [24576,32768)
// Dual-row packed swizzle (2 lanes/bank); gll16 linear dest + inverse-swizzled
// source (rule #21). Phase = {ds_read subtile; issue stage; barrier;
// setprio+16 MFMA; barrier}. vmcnt counted ONCE per K-tile (T4).

// ---- G1: h = silu(x@w1)*(x@wg)  (e<7)  |  silu(x@sw1 + sb1)  (e==7) ---------
// Double-buffer (128 KB); stages for kt+1 issued in phases 0-1, vmcnt(0) at
// K-tile end (youngest load then 2 phases old -> drain pre-covered).
__global__ void __launch_bounds__(512, 2)
g1_kernel(const ushort* __restrict__ Xb, const ushort* __restrict__ W1,
          const ushort* __restrict__ WG, const float* __restrict__ sb1,
          ushort* __restrict__ H, const int* __restrict__ row_tok,
          const int* __restrict__ ctrl)
{
    __shared__ ushort lds[65536];   // 128 KB: 2 bufs x 32768
    int bx, col0;
    xcd_remap(bx, col0);
    if (bx >= ctrl[0]) return;
    const int e     = ctrl[32 + 2*bx];
    const int slot0 = ctrl[32 + 2*bx + 1];
    const bool gated = (e != NE);
    const int tt = threadIdx.x;
    const int lane = tt & 63, wid = tt >> 6;
    const int wm = wid >> 2, wn = wid & 3;
    const int wofs = wid * 512;

    // staging source (inverse-swizzled global address), 16B per lane
    const int slog = (tt & 7) ^ ((tt >> 3) & 7);
    const int kk0 = (slog & 3) * 8;
    const int r0 = ((tt >> 3) << 1) + (slog >> 2);
    const ushort* pA0 = Xb + (size_t)row_tok[slot0 + r0] * DIM + kk0;
    const ushort* pA1 = Xb + (size_t)row_tok[slot0 + r0 + 128] * DIM + kk0;
    const ushort* B1e = W1 + (size_t)e * (DIM*DIM);
    const ushort* B2e = gated ? (WG + (size_t)e * (DIM*DIM))
                              : (W1 + (size_t)NE * (DIM*DIM));
    const ushort* pB1 = B1e + (size_t)(col0 + r0) * DIM + kk0;
    const ushort* pB2 = B2e + (size_t)(col0 + r0) * DIM + kk0;

    // fragment read offsets (swizzled, subtile-relative)
    const int hi = lane >> 4, lr = lane & 15;
    int aoffb[8], boffb[2];
#pragma unroll
    for (int mf = 0; mf < 8; mf++) {
        int row = wm*128 + mf*16 + lr;
        int lrow = row >> 1;
        int sl = ((row & 1) << 2) | hi;
        aoffb[mf] = lrow*64 + (sl ^ (lrow & 7))*8;
    }
#pragma unroll
    for (int nf = 0; nf < 2; nf++) {
        int oc = wn*32 + nf*16 + lr;
        int lrow = oc >> 1;
        int sl = ((oc & 1) << 2) | hi;
        boffb[nf] = lrow*64 + (sl ^ (lrow & 7))*8;
    }

    f32x4 zero4 = {0.f, 0.f, 0.f, 0.f};
    f32x4 acc1[8][2], acc2[8][2];
#pragma unroll
    for (int mf = 0; mf < 8; mf++)
#pragma unroll
        for (int nf = 0; nf < 2; nf++) { acc1[mf][nf] = zero4; acc2[mf][nf] = zero4; }

    auto stageks = [&](int buf, int kt, int ks) {
        ushort* b = &lds[buf * 32768];
        int gk = kt * 64 + ks * 32;
        gll16(pA0 + gk, b + ks*8192 + wofs);
        gll16(pA1 + gk, b + ks*8192 + 4096 + wofs);
        gll16(pB1 + gk, b + 16384 + ks*4096 + wofs);
        gll16(pB2 + gk, b + 24576 + ks*4096 + wofs);
    };

    // prologue: K-tile 0 into buf 0
    stageks(0, 0, 0); stageks(0, 0, 1);
    asm volatile("s_waitcnt vmcnt(0)" ::: "memory");
    __builtin_amdgcn_s_barrier();
    asm volatile("" ::: "memory");

    for (int kt = 0; kt < 16; ++kt) {
        const int cur = kt & 1;
        const ushort* L = &lds[cur * 32768];
#pragma unroll
        for (int p = 0; p < 4; ++p) {
            const int mh = p >> 1, ks = p & 1;
            bf16x8 a[4], b1f[2], b2f[2];
#pragma unroll
            for (int j = 0; j < 4; j++)
                a[j] = *(const bf16x8*)(L + ks*8192 + aoffb[4*mh + j]);
#pragma unroll
            for (int n = 0; n < 2; n++) {
                b1f[n] = *(const bf16x8*)(L + 16384 + ks*4096 + boffb[n]);
                b2f[n] = *(const bf16x8*)(L + 24576 + ks*4096 + boffb[n]);
            }
            if (p < 2 && kt < 15) stageks(cur ^ 1, kt + 1, p);
            __builtin_amdgcn_s_barrier();
            asm volatile("" ::: "memory");
            __builtin_amdgcn_s_setprio(1);
#pragma unroll
            for (int j = 0; j < 4; j++)
#pragma unroll
                for (int n = 0; n < 2; n++) {
                    acc1[4*mh+j][n] = __builtin_amdgcn_mfma_f32_16x16x32_bf16(a[j], b1f[n], acc1[4*mh+j][n], 0, 0, 0);
                    acc2[4*mh+j][n] = __builtin_amdgcn_mfma_f32_16x16x32_bf16(a[j], b2f[n], acc2[4*mh+j][n], 0, 0, 0);
                }
            __builtin_amdgcn_s_setprio(0);
            if (p == 3) asm volatile("s_waitcnt vmcnt(0)" ::: "memory");
            __builtin_amdgcn_s_barrier();
            asm volatile("" ::: "memory");
        }
    }

    // epilogue: SwiGLU (routed) / bias-silu (shared)
#pragma unroll
    for (int mf = 0; mf < 8; mf++)
#pragma unroll
        for (int nf = 0; nf < 2; nf++)
#pragma unroll
            for (int r = 0; r < 4; r++) {
                int row = slot0 + wm*128 + mf*16 + hi*4 + r;
                int col = col0 + wn*32 + nf*16 + lr;
                float v1 = acc1[mf][nf][r];
                float h = gated ? siluf(v1) * acc2[mf][nf][r]
                                : siluf(v1 + sb1[col]);
                H[(size_t)row * DIM + col] = f2bf(h);
            }
}

// ---- G2: y = h @ w2 ; routed -> y2 bf16 ; shared -> out = y + sb2 (fp32) ----
// Triple-buffer (144 KB), true counted vmcnt(6): stage kt+2 during kt, loads
// span K-tiles (never drained to 0 in the main loop).
__global__ void __launch_bounds__(512, 2)
g2_kernel(const ushort* __restrict__ H, const ushort* __restrict__ W2,
          const float* __restrict__ sb2, float* __restrict__ out,
          ushort* __restrict__ y2, const int* __restrict__ ctrl)
{
    __shared__ ushort lds[73728];   // 144 KB: 3 bufs x 24576 (A 16384 + B 8192)
    int bx, col0;
    xcd_remap(bx, col0);
    if (bx >= ctrl[0]) return;
    const int e     = ctrl[32 + 2*bx];
    const int slot0 = ctrl[32 + 2*bx + 1];
    const int sbase = ctrl[2];
    const int tt = threadIdx.x;
    const int lane = tt & 63, wid = tt >> 6;
    const int wm = wid >> 2, wn = wid & 3;
    const int wofs = wid * 512;

    const int slog = (tt & 7) ^ ((tt >> 3) & 7);
    const int kk0 = (slog & 3) * 8;
    const int r0 = ((tt >> 3) << 1) + (slog >> 2);
    const ushort* pA0 = H + (size_t)(slot0 + r0) * DIM + kk0;
    const ushort* pA1 = H + (size_t)(slot0 + r0 + 128) * DIM + kk0;
    const ushort* Be  = W2 + (size_t)e * (DIM*DIM);
    const ushort* pB1 = Be + (size_t)(col0 + r0) * DIM + kk0;

    const int hi = lane >> 4, lr = lane & 15;
    int aoffb[8], boffb[2];
#pragma unroll
    for (int mf = 0; mf < 8; mf++) {
        int row = wm*128 + mf*16 + lr;
        int lrow = row >> 1;
        int sl = ((row & 1) << 2) | hi;
        aoffb[mf] = lrow*64 + (sl ^ (lrow & 7))*8;
    }
#pragma unroll
    for (int nf = 0; nf < 2; nf++) {
        int oc = wn*32 + nf*16 + lr;
        int lrow = oc >> 1;
        int sl = ((oc & 1) << 2) | hi;
        boffb[nf] = lrow*64 + (sl ^ (lrow & 7))*8;
    }

    f32x4 zero4 = {0.f, 0.f, 0.f, 0.f};
    f32x4 acc[8][2];
#pragma unroll
    for (int mf = 0; mf < 8; mf++)
#pragma unroll
        for (int nf = 0; nf < 2; nf++) acc[mf][nf] = zero4;

    auto stageks = [&](int buf, int kt, int ks) {
        ushort* b = &lds[buf * 24576];
        int gk = kt * 64 + ks * 32;
        gll16(pA0 + gk, b + ks*8192 + wofs);
        gll16(pA1 + gk, b + ks*8192 + 4096 + wofs);
        gll16(pB1 + gk, b + 16384 + ks*4096 + wofs);
    };

    // prologue: kt0 -> buf0, kt1 -> buf1; wait kt0 (6 of 12 outstanding)
    stageks(0, 0, 0); stageks(0, 0, 1);
    stageks(1, 1, 0); stageks(1, 1, 1);
    asm volatile("s_waitcnt vmcnt(6)" ::: "memory");
    __builtin_amdgcn_s_barrier();
    asm volatile("" ::: "memory");

    int cur = 0;
    for (int kt = 0; kt < 16; ++kt) {
        const ushort* L = &lds[cur * 24576];
        const int nbuf = (cur == 0) ? 2 : (cur - 1);   // (cur+2)%3
        const bool dostage = (kt + 2 < 16);
#pragma unroll
        for (int p = 0; p < 2; ++p) {                  // p = kslice
            bf16x8 a[8], bf[2];
#pragma unroll
            for (int mf = 0; mf < 8; mf++)
                a[mf] = *(const bf16x8*)(L + p*8192 + aoffb[mf]);
#pragma unroll
            for (int n = 0; n < 2; n++)
                bf[n] = *(const bf16x8*)(L + 16384 + p*4096 + boffb[n]);
            if (dostage) stageks(nbuf, kt + 2, p);
            __builtin_amdgcn_s_barrier();
            asm volatile("" ::: "memory");
            __builtin_amdgcn_s_setprio(1);
#pragma unroll
            for (int mf = 0; mf < 8; mf++)
#pragma unroll
                for (int n = 0; n < 2; n++)
                    acc[mf][n] = __builtin_amdgcn_mfma_f32_16x16x32_bf16(a[mf], bf[n], acc[mf][n], 0, 0, 0);
            __builtin_amdgcn_s_setprio(0);
            if (p == 1) {
                if (kt < 14) asm volatile("s_waitcnt vmcnt(6)" ::: "memory");
                else         asm volatile("s_waitcnt vmcnt(0)" ::: "memory");
            }
            __builtin_amdgcn_s_barrier();
            asm volatile("" ::: "memory");
        }
        cur = (cur == 2) ? 0 : cur + 1;
    }

#pragma unroll
    for (int mf = 0; mf < 8; mf++)
#pragma unroll
        for (int nf = 0; nf < 2; nf++)
#pragma unroll
            for (int r = 0; r < 4; r++) {
                int row = slot0 + wm*128 + mf*16 + hi*4 + r;
                int col = col0 + wn*32 + nf*16 + lr;
                float v = acc[mf][nf][r];
                if (e != NE) y2[(size_t)row * DIM + col] = f2bf(v);
                else         out[(size_t)(row - sbase) * DIM + col] = v + sb2[col];
            }
}

// --------- combine: out[n] += sum_k w_k * y2[slot_k(n)] ----------------------
__global__ void __launch_bounds__(256)
combine_kernel(const ushort* __restrict__ y2, const int* __restrict__ slots,
               const float* __restrict__ topk_w, float* __restrict__ out)
{
    __shared__ int ss[3];
    __shared__ float sw[3];
    const int n = blockIdx.x, tid = threadIdx.x;
    if (tid < 3) { ss[tid] = slots[n * 3 + tid]; sw[tid] = topk_w[n * 3 + tid]; }
    __syncthreads();
    float4* o4 = (float4*)(out + (size_t)n * DIM);
    float4 o = o4[tid];
#pragma unroll
    for (int k = 0; k < 3; k++) {
        const ushort4 yv = *(const ushort4*)(y2 + (size_t)ss[k] * DIM + tid * 4);
        float w = sw[k];
        o.x += w * bf2f(yv.x);
        o.y += w * bf2f(yv.y);
        o.z += w * bf2f(yv.z);
        o.w += w * bf2f(yv.w);
    }
    o4[tid] = o;
}

extern "C" void kernel_launch(void* const* d_in, const int* in_sizes, int n_in,
                              void* d_out, int out_size, void* d_ws, size_t ws_size,
                              hipStream_t stream)
{
    const float* x    = (const float*)d_in[0];
    const float* gw   = (const float*)d_in[1];
    const float* gb   = (const float*)d_in[2];
    const float* bia  = (const float*)d_in[3];
    const float* w1   = (const float*)d_in[4];
    const float* wg   = (const float*)d_in[5];
    const float* w2   = (const float*)d_in[6];
    const float* sw1  = (const float*)d_in[7];
    const float* sb1  = (const float*)d_in[8];
    const float* sw2  = (const float*)d_in[9];
    const float* sb2  = (const float*)d_in[10];
    float* out = (float*)d_out;

    // Workspace layout (bytes); total 173,452,288 <= proven ws_size >= 186,625,024.
    char* ws = (char*)d_ws;
    int*    ctrl   = (int*)   (ws + 0);          // [0]=ntiles [1]=rows [2]=shared_base, +8 counts, +16 cursors, +32 tiles
    int*    topk_e = (int*)   (ws + 4096);       //  98,304
    float*  topk_w = (float*) (ws + 102400);     //  98,304
    int*    slots  = (int*)   (ws + 200704);     //  98,304
    int*    row_tok= (int*)   (ws + 299008);     // 138,240 (34560 ints) -> pad to 437,248
    ushort* w1T    = (ushort*)(ws + 437248);     // 8 x 2MB (e7 = sw1T)
    ushort* wgT    = (ushort*)(ws + 17214464);   // 7 x 2MB
    ushort* w2T    = (ushort*)(ws + 31894528);   // 8 x 2MB (e7 = sw2T)
    ushort* h1     = (ushort*)(ws + 48671744);   // 34560 x 1024 bf16 = 70,778,880
    ushort* y2     = (ushort*)(ws + 119450624);  // 26368 x 1024 bf16 = 54,001,664 -> end 173,452,288
    ushort* xb     = y2;                         // alias: xb dead before g2 writes y2

    hipMemsetAsync(ctrl, 0, 4096, stream);
    hipMemsetAsync(row_tok, 0, 34560 * 4, stream);   // pad slots default to token 0
    transpose_convert<<<dim3(32, 32, 23), 256, 0, stream>>>(w1, wg, w2, sw1, sw2,
                                                            w1T, wgT, w2T);
    gate_kernel<<<N_TOK / 16, 256, 0, stream>>>(x, gw, gb, bia, topk_e, topk_w,
                                                ctrl + 8, xb);
    setup_kernel<<<1, 64, 0, stream>>>(ctrl);
    ident_kernel<<<N_TOK / 256, 256, 0, stream>>>(ctrl, row_tok);
    scatter_kernel<<<N_TOK / 256, 256, 0, stream>>>(topk_e, topk_w, ctrl, row_tok,
                                                    slots);

    g1_kernel<<<dim3(MT_TILES, 8), 512, 0, stream>>>(xb, w1T, wgT, sb1, h1,
                                                     row_tok, ctrl);
    g2_kernel<<<dim3(MT_TILES, 8), 512, 0, stream>>>(h1, w2T, sb2, out, y2, ctrl);
    combine_kernel<<<N_TOK, 256, 0, stream>>>(y2, slots, topk_w, out);
}